// Round 1
// baseline (213.702 us; speedup 1.0000x reference)
//
#include <hip/hip_runtime.h>
#include <hip/hip_bf16.h>
#include <math.h>

// Problem constants
#define B_   8
#define H_   8
#define S_   2048
#define D_   64      // head dim
#define BH_  64      // B*H
#define DPROJ_ 512

typedef __attribute__((ext_vector_type(8)))  _Float16 f16x8;
typedef __attribute__((ext_vector_type(4)))  float    f32x4;
typedef __attribute__((ext_vector_type(16))) float    f32x16;
typedef __attribute__((ext_vector_type(4)))  int      i32x4;

static __device__ __forceinline__ short f16bits(float f) {
    return __builtin_bit_cast(short, (_Float16)f);   // v_cvt_f16_f32 (RNE)
}

static __device__ __forceinline__ f16x8 load8_f32_f16(const float* p) {
    const float4 a = ((const float4*)p)[0];
    const float4 b = ((const float4*)p)[1];
    f16x8 r;
    r[0] = (_Float16)a.x; r[1] = (_Float16)a.y; r[2] = (_Float16)a.z; r[3] = (_Float16)a.w;
    r[4] = (_Float16)b.x; r[5] = (_Float16)b.y; r[6] = (_Float16)b.z; r[7] = (_Float16)b.w;
    return r;
}

// ---------------------------------------------------------------------------
// Kernel 1a: Q/K projection.
//   q_ws,k_ws: [BH][S][64] f16.
//   q pre-scaled by 0.1125*log2(e) so flash can use exp2 directly (saves the
//   per-element ln2 multiply in the softmax hot loop).
// ---------------------------------------------------------------------------
#define QKST 520

__global__ __launch_bounds__(256)
void proj_qk_kernel(const float* __restrict__ query, const float* __restrict__ key,
                    const float* __restrict__ Wq, const float* __restrict__ bq,
                    const float* __restrict__ Wk, const float* __restrict__ bk,
                    short* __restrict__ qws, short* __restrict__ kws)
{
    __shared__ __align__(16) short tile[16 * QKST];

    const int tid  = threadIdx.x;
    const int wave = tid >> 6;
    const int lane = tid & 63;
    const int n    = lane & 15;
    const int quad = lane >> 4;
    const int r0   = blockIdx.x * 16;
    const int kind = blockIdx.y;             // 0=q, 1=k
    const int b    = r0 >> 11;
    const int s0   = r0 & 2047;
    // (1-dropout)/num_heads/... = 0.9/8 = 0.1125, times log2(e) for exp2 softmax
    const float QS = 0.16230319188537014f;

    const float* X    = kind ? key : query;
    const float* W    = kind ? Wk  : Wq;
    const float* bias = kind ? bk  : bq;
    short*       ows  = kind ? kws : qws;

    f16x8 af = load8_f32_f16(X + (r0 + n) * 32 + quad * 8);
    #pragma unroll
    for (int i = 0; i < 8; ++i) {
        const int c0 = wave * 128 + i * 16;
        f16x8 bfr = load8_f32_f16(W + (c0 + n) * 32 + quad * 8);
        f32x4 acc = {0.f, 0.f, 0.f, 0.f};
        acc = __builtin_amdgcn_mfma_f32_16x16x32_f16(af, bfr, acc, 0, 0, 0);
        const int c = c0 + n;
        const float bsf = bias[c];
        #pragma unroll
        for (int r = 0; r < 4; ++r) {
            float v = acc[r] + bsf;
            if (kind == 0) v *= QS;
            tile[(quad * 4 + r) * QKST + c] = f16bits(v);
        }
    }
    __syncthreads();

    #pragma unroll
    for (int k = 0; k < 4; ++k) {
        const int slot = k * 256 + tid;
        const int li   = slot & 7;
        const int chunk= slot >> 3;
        const int row  = chunk & 15;
        const int h    = chunk >> 4;
        uint4 vv = *(const uint4*)(tile + row * QKST + h * 64 + li * 8);
        *(uint4*)(ows + ((size_t)(b * 8 + h) * S_ + s0 + row) * 64 + li * 8) = vv;
    }
}

// ---------------------------------------------------------------------------
// Kernel 1b: V projection. Blocked output layout:
//   v_ws[bh][s_tile][d][ks]  (s_tile = s/32, ks = s%32)  f16
// so each 32-k V^T tile is a contiguous 4 KB chunk for flash LDS staging.
// ---------------------------------------------------------------------------
__global__ __launch_bounds__(256)
void proj_v_kernel(const float* __restrict__ value,
                   const float* __restrict__ Wv, const float* __restrict__ bv,
                   short* __restrict__ vws)
{
    __shared__ __align__(16) short vtile[2 * 256 * 32];   // 32 KB

    const int tid  = threadIdx.x;
    const int wave = tid >> 6;
    const int lane = tid & 63;
    const int n    = lane & 15;
    const int quad = lane >> 4;
    const int r0   = blockIdx.x * 64;
    const int cb   = blockIdx.y * 256;
    const int b    = r0 >> 11;
    const int s0   = r0 & 2047;
    const int sub  = wave >> 1;
    const int sh   = (wave & 1) * 16;

    f16x8 bfr = load8_f32_f16(value + (r0 + sub * 32 + sh + n) * 32 + quad * 8);
    #pragma unroll
    for (int i = 0; i < 16; ++i) {
        const int c0 = cb + i * 16;
        f16x8 af = load8_f32_f16(Wv + (c0 + n) * 32 + quad * 8);
        f32x4 acc = {0.f, 0.f, 0.f, 0.f};
        acc = __builtin_amdgcn_mfma_f32_16x16x32_f16(af, bfr, acc, 0, 0, 0);
        #pragma unroll
        for (int r = 0; r < 4; ++r) {
            const int dc = c0 + quad * 4 + r;
            float v = acc[r] + bv[dc];
            vtile[(sub * 256 + (dc - cb)) * 32 + sh + n] = f16bits(v);
        }
    }
    __syncthreads();

    #pragma unroll
    for (int k = 0; k < 8; ++k) {
        const int slot = k * 256 + tid;
        const int li   = slot & 3;
        const int cl   = (slot >> 2) & 255;
        const int sb   = slot >> 10;
        const int c    = cb + cl;
        const int bh   = b * 8 + (c >> 6);
        const int d    = c & 63;
        const int stile= (s0 >> 5) + sb;
        uint4 vv = *(const uint4*)(vtile + (sb * 256 + cl) * 32 + li * 8);
        *(uint4*)(vws + (((size_t)bh * (S_ / 32) + stile) * 64 + d) * 32 + li * 8) = vv;
    }
}

// ---------------------------------------------------------------------------
// Kernel 2: flash attention. R7: OCCUPANCY restructure.
// Was: 4 waves/block x 64 q-rows -> 8 waves/CU (2/SIMD): TRANS(exp)+VALU+MFMA
// +LDS chains could not overlap (MfmaUtil 30 + VALUBusy 42, 27% dead).
// Now: 8 waves/block (512 thr) x 32 q-rows, same 512-block grid
//   -> 2 blocks/CU x 8 waves = 16 waves/CU (4/SIMD).
// Epilogue transposes one 32x32 d-tile at a time (32x36 f32 per wave) so
// static LDS = 56.3 KB < 64 KB and 2 blocks/CU still fit.
// Grid swapped to (BH, S/256): linear block id === bh (mod 8) -> all 8
// q-tile blocks of one head share an XCD; K/V working set 4 MB/XCD ~= L2.
// Staging: threads 0-255 stage K (16B each), 256-511 stage V; double
// buffered, 2-barrier loop (proven correct, unchanged).
// Softmax uses exp2 (scale pre-folded into Q projection).
// ---------------------------------------------------------------------------
#define KST 72   // K lds row stride (shorts): 144B, 16B-aligned
#define VST 40   // V lds row stride (shorts): 80B, 16B-aligned
#define OTS 36   // epilogue LDS row stride (f32) for one 32-wide d-tile

__global__ __launch_bounds__(512, 4)
void flash_kernel(const short* __restrict__ qws, const short* __restrict__ kws,
                  const short* __restrict__ vws, float* __restrict__ out)
{
    __shared__ __align__(16) short ldsk[2 * 32 * KST];   //  9216 B
    __shared__ __align__(16) short ldsv[2 * 64 * VST];   // 10240 B
    __shared__ __align__(16) float olds[8 * 32 * OTS];   // 36864 B  (tot 56320)

    const int tid  = threadIdx.x;
    const int wave = tid >> 6;
    const int lane = tid & 63;
    const int m32  = lane & 31;
    const int lh   = lane >> 5;          // lane-half
    const int koff = lh * 8;
    const bool lh0 = (lh == 0);
    const int bh   = blockIdx.x;                     // XCD = bh % 8
    const int q0   = blockIdx.y * 256 + wave * 32;   // 32 q-rows per wave

    const short* qbase = qws + (size_t)bh * S_ * D_;
    const short* kbase = kws + (size_t)bh * S_ * D_;
    const short* vbase = vws + (size_t)bh * (S_ / 32) * 2048;  // blocked tiles

    // staging role: tid<256 -> K (32x64, 8 thr/row), else V (64x32, 4 thr/row)
    const bool doK = (tid < 256);
    const int  st_t = doK ? tid : (tid - 256);
    short* sdst0 = doK ? (ldsk + (st_t >> 3) * KST + (st_t & 7) * 8)
                       : (ldsv + (st_t >> 2) * VST + (st_t & 3) * 8);
    const short* sbase = doK ? kbase : vbase;
    const int  sbufstride = doK ? (32 * KST) : (64 * VST);

    // Q^T B-frags (held): qb[h]: B[d=h*16+lh*8+j][q=m32]
    f16x8 qb[4];
    #pragma unroll
    for (int h = 0; h < 4; ++h)
        qb[h] = *(const f16x8*)(qbase + (q0 + m32) * D_ + h * 16 + koff);

    f32x16 o0, o1;       // O^T accumulators, d-tiles 0/1
    float  pl = 0.f;
    #pragma unroll
    for (int r = 0; r < 16; ++r) { o0[r] = 0.f; o1[r] = 0.f; }

    // stage tile 0 into buffer 0  (one coalesced 16B load per thread)
    {
        uint4 sr = *(const uint4*)(sbase + (size_t)st_t * 8);
        *(uint4*)sdst0 = sr;
    }
    __syncthreads();

    for (int it = 0; it < 64; ++it) {
        const int cur = it & 1, nx = cur ^ 1;

        // issue next-tile global load early (coalesced 16B/thread, 4KB each)
        uint4 sr;
        if (it < 63)
            sr = *(const uint4*)(sbase + (size_t)(it + 1) * 2048 + st_t * 8);

        // ---- compute on buffer cur ----
        const short* kl = ldsk + cur * (32 * KST);
        const short* vl = ldsv + cur * (64 * VST);
        f16x8 kf[4], va[4];
        #pragma unroll
        for (int h = 0; h < 4; ++h)
            kf[h] = *(const f16x8*)(kl + m32 * KST + h * 16 + koff);
        #pragma unroll
        for (int t = 0; t < 2; ++t)
            #pragma unroll
            for (int kh = 0; kh < 2; ++kh)
                va[t * 2 + kh] = *(const f16x8*)(vl + (t * 32 + m32) * VST + kh * 16 + koff);

        f32x16 st;
        #pragma unroll
        for (int r = 0; r < 16; ++r) st[r] = 0.f;
        #pragma unroll
        for (int h = 0; h < 4; ++h)
            st = __builtin_amdgcn_mfma_f32_32x32x16_f16(kf[h], qb[h], st, 0, 0, 0);

        // softmax numerator: p = 2^st  (log2(e) folded into Q projection)
        #pragma unroll
        for (int r = 0; r < 16; ++r) st[r] = exp2f(st[r]);
        {
            float s01 = (st[0]+st[1]) + (st[2]+st[3]);
            float s23 = (st[4]+st[5]) + (st[6]+st[7]);
            float s45 = (st[8]+st[9]) + (st[10]+st[11]);
            float s67 = (st[12]+st[13]) + (st[14]+st[15]);
            pl += (s01 + s23) + (s45 + s67);
        }

        unsigned int pk[8], xk[8];
        #pragma unroll
        for (int i = 0; i < 8; ++i)
            pk[i] = __builtin_bit_cast(unsigned int,
                      __builtin_amdgcn_cvt_pkrtz(st[2 * i], st[2 * i + 1]));
        #pragma unroll
        for (int i = 0; i < 8; ++i)
            xk[i] = (unsigned int)__shfl_xor((int)pk[i], 32);

        i32x4 bi0, bi1;
        bi0[0] = (int)(lh0 ? pk[0] : xk[2]);
        bi0[1] = (int)(lh0 ? pk[1] : xk[3]);
        bi0[2] = (int)(lh0 ? xk[0] : pk[2]);
        bi0[3] = (int)(lh0 ? xk[1] : pk[3]);
        bi1[0] = (int)(lh0 ? pk[4] : xk[6]);
        bi1[1] = (int)(lh0 ? pk[5] : xk[7]);
        bi1[2] = (int)(lh0 ? xk[4] : pk[6]);
        bi1[3] = (int)(lh0 ? xk[5] : pk[7]);
        f16x8 bf0 = __builtin_bit_cast(f16x8, bi0);
        f16x8 bf1 = __builtin_bit_cast(f16x8, bi1);

        o0 = __builtin_amdgcn_mfma_f32_32x32x16_f16(va[0], bf0, o0, 0, 0, 0);
        o0 = __builtin_amdgcn_mfma_f32_32x32x16_f16(va[1], bf1, o0, 0, 0, 0);
        o1 = __builtin_amdgcn_mfma_f32_32x32x16_f16(va[2], bf0, o1, 0, 0, 0);
        o1 = __builtin_amdgcn_mfma_f32_32x32x16_f16(va[3], bf1, o1, 0, 0, 0);

        __syncthreads();   // all waves done reading buffer cur
        if (it < 63)
            *(uint4*)(sdst0 + nx * sbufstride) = sr;
        __syncthreads();   // staging visible before next iter's reads
    }

    // epilogue: complete row sums across lane-halves, normalize, transpose
    // O^T -> O one 32-wide d-tile at a time through per-wave LDS (32x36 f32),
    // coalesced f32x4 stores (128B per 8 lanes).
    const int b = bh >> 3, h = bh & 7;
    float* ow = olds + wave * (32 * OTS);
    const float rs = pl + __shfl_xor(pl, 32);
    const float rl = 1.0f / rs;

    #pragma unroll
    for (int t = 0; t < 2; ++t) {
        const f32x16& ot = t ? o1 : o0;
        #pragma unroll
        for (int g = 0; g < 4; ++g) {
            f32x4 w;
            w[0] = ot[g * 4 + 0] * rl;
            w[1] = ot[g * 4 + 1] * rl;
            w[2] = ot[g * 4 + 2] * rl;
            w[3] = ot[g * 4 + 3] * rl;
            // element (q=m32, dcol=(0..3)+8g+4lh) of this 32-wide tile
            *(f32x4*)(ow + m32 * OTS + 8 * g + 4 * lh) = w;
        }
        #pragma unroll
        for (int c = 0; c < 4; ++c) {
            const int row = (lane >> 3) + 8 * c;       // q-row within wave tile
            f32x4 v = *(const f32x4*)(ow + row * OTS + (lane & 7) * 4);
            const int sq = q0 + row;
            *(f32x4*)(out + ((size_t)(b * S_ + sq)) * DPROJ_
                          + h * 64 + t * 32 + (lane & 7) * 4) = v;
        }
    }
}

// ---------------------------------------------------------------------------
extern "C" void kernel_launch(void* const* d_in, const int* in_sizes, int n_in,
                              void* d_out, int out_size, void* d_ws, size_t ws_size,
                              hipStream_t stream)
{
    const float* query = (const float*)d_in[0];
    const float* key   = (const float*)d_in[1];
    const float* value = (const float*)d_in[2];
    // d_in[3] = mask (int32) -- only its shape feeds the reference; unused.
    const float* Wq = (const float*)d_in[4];
    const float* bq = (const float*)d_in[5];
    const float* Wk = (const float*)d_in[6];
    const float* bk = (const float*)d_in[7];
    const float* Wv = (const float*)d_in[8];
    const float* bv = (const float*)d_in[9];

    float* out = (float*)d_out;
    short* ws  = (short*)d_ws;
    const size_t TSZ = (size_t)BH_ * S_ * D_;
    short* qws = ws;
    short* kws = ws + TSZ;
    short* vws = ws + 2 * TSZ;

    proj_qk_kernel<<<dim3((B_ * S_) / 16, 2), 256, 0, stream>>>(
        query, key, Wq, bq, Wk, bk, qws, kws);
    proj_v_kernel<<<dim3((B_ * S_) / 64, 2), 256, 0, stream>>>(
        value, Wv, bv, vws);
    flash_kernel<<<dim3(BH_, S_ / 256), 512, 0, stream>>>(qws, kws, vws, out);
}

// Round 2
// 184.875 us; speedup vs baseline: 1.1559x; 1.1559x over previous
//
#include <hip/hip_runtime.h>
#include <hip/hip_bf16.h>
#include <math.h>

// Problem constants
#define B_   8
#define H_   8
#define S_   2048
#define D_   64      // head dim
#define BH_  64      // B*H
#define DPROJ_ 512

typedef __attribute__((ext_vector_type(8)))  _Float16 f16x8;
typedef __attribute__((ext_vector_type(4)))  float    f32x4;
typedef __attribute__((ext_vector_type(16))) float    f32x16;
typedef __attribute__((ext_vector_type(4)))  int      i32x4;

static __device__ __forceinline__ short f16bits(float f) {
    return __builtin_bit_cast(short, (_Float16)f);   // v_cvt_f16_f32 (RNE)
}

static __device__ __forceinline__ f16x8 load8_f32_f16(const float* p) {
    const float4 a = ((const float4*)p)[0];
    const float4 b = ((const float4*)p)[1];
    f16x8 r;
    r[0] = (_Float16)a.x; r[1] = (_Float16)a.y; r[2] = (_Float16)a.z; r[3] = (_Float16)a.w;
    r[4] = (_Float16)b.x; r[5] = (_Float16)b.y; r[6] = (_Float16)b.z; r[7] = (_Float16)b.w;
    return r;
}

// exp2: guarantee a single v_exp_f32 (HW computes 2^x)
#if __has_builtin(__builtin_amdgcn_exp2f)
#define EXP2(x) __builtin_amdgcn_exp2f(x)
#else
#define EXP2(x) exp2f(x)
#endif

// permlane32_swap: newA = {A_lo, B_lo}, newB = {A_hi, B_hi}.
// Replaces (shfl_xor 32 + 2x cndmask) per register pair.
static __device__ __forceinline__ void pl32swap(unsigned int& a, unsigned int& b) {
#if __has_builtin(__builtin_amdgcn_permlane32_swap)
    auto r = __builtin_amdgcn_permlane32_swap((int)a, (int)b, false, false);
    a = (unsigned int)r[0];
    b = (unsigned int)r[1];
#else
    const bool lh0 = ((threadIdx.x & 63) < 32);
    unsigned int xa = (unsigned int)__shfl_xor((int)a, 32);
    unsigned int xb = (unsigned int)__shfl_xor((int)b, 32);
    unsigned int na = lh0 ? a : xb;
    unsigned int nb = lh0 ? xa : b;
    a = na; b = nb;
#endif
}

// ---------------------------------------------------------------------------
// Fused projection kernel: one launch does Q, K (kind 0/1) and V (kind 2).
// Previously two serialized kernels on the stream; fusing lets all three
// proj workloads fill the GPU concurrently.
//   q_ws,k_ws: [BH][S][64] f16; q pre-scaled by 0.1125*log2(e) (exp2 softmax).
//   v_ws: blocked [bh][s_tile][d][ks] (s_tile=s/32, ks=s%32) f16 so each
//   32-k V^T tile is a contiguous 4 KB chunk for flash LDS staging.
// ---------------------------------------------------------------------------
#define QKST 520

__global__ __launch_bounds__(256)
void proj_kernel(const float* __restrict__ query, const float* __restrict__ key,
                 const float* __restrict__ value,
                 const float* __restrict__ Wq, const float* __restrict__ bq,
                 const float* __restrict__ Wk, const float* __restrict__ bk,
                 const float* __restrict__ Wv, const float* __restrict__ bv,
                 short* __restrict__ qws, short* __restrict__ kws,
                 short* __restrict__ vws)
{
    __shared__ __align__(16) short shbuf[16384];   // 32 KB, unioned per path

    const int tid  = threadIdx.x;
    const int wave = tid >> 6;
    const int lane = tid & 63;
    const int n    = lane & 15;
    const int quad = lane >> 4;
    const int kind = blockIdx.y;             // 0=q, 1=k, 2=v

    if (kind < 2) {
        short* tile = shbuf;                 // 16 x QKST = 16640 B
        const int r0   = blockIdx.x * 16;
        const int b    = r0 >> 11;
        const int s0   = r0 & 2047;
        // (1-dropout)/num_heads = 0.9/8 = 0.1125, times log2(e) for exp2 softmax
        const float QS = 0.16230319188537014f;

        const float* X    = kind ? key : query;
        const float* W    = kind ? Wk  : Wq;
        const float* bias = kind ? bk  : bq;
        short*       ows  = kind ? kws : qws;

        f16x8 af = load8_f32_f16(X + (r0 + n) * 32 + quad * 8);
        #pragma unroll
        for (int i = 0; i < 8; ++i) {
            const int c0 = wave * 128 + i * 16;
            f16x8 bfr = load8_f32_f16(W + (c0 + n) * 32 + quad * 8);
            f32x4 acc = {0.f, 0.f, 0.f, 0.f};
            acc = __builtin_amdgcn_mfma_f32_16x16x32_f16(af, bfr, acc, 0, 0, 0);
            const int c = c0 + n;
            const float bsf = bias[c];
            #pragma unroll
            for (int r = 0; r < 4; ++r) {
                float v = acc[r] + bsf;
                if (kind == 0) v *= QS;
                tile[(quad * 4 + r) * QKST + c] = f16bits(v);
            }
        }
        __syncthreads();

        #pragma unroll
        for (int k = 0; k < 4; ++k) {
            const int slot = k * 256 + tid;
            const int li   = slot & 7;
            const int chunk= slot >> 3;
            const int row  = chunk & 15;
            const int h    = chunk >> 4;
            uint4 vv = *(const uint4*)(tile + row * QKST + h * 64 + li * 8);
            *(uint4*)(ows + ((size_t)(b * 8 + h) * S_ + s0 + row) * 64 + li * 8) = vv;
        }
    } else {
        if (blockIdx.x >= 256) return;       // v path needs only 256 blocks
        short* vtile = shbuf;                // 2*256*32 shorts = 32768 B
        const int r0   = blockIdx.x * 64;
        const int cb   = 0;                  // v covers all 512 cols per row-block
        const int b    = r0 >> 11;
        const int s0   = r0 & 2047;
        const int sub  = wave >> 1;
        const int sh   = (wave & 1) * 16;

        // two 256-col halves sequentially (vtile holds 2 x 256 cols x 32 s)
        #pragma unroll
        for (int half = 0; half < 2; ++half) {
            const int cbh = half * 256;
            f16x8 bfr = load8_f32_f16(value + (r0 + sub * 32 + sh + n) * 32 + quad * 8);
            #pragma unroll
            for (int i = 0; i < 16; ++i) {
                const int c0 = cbh + i * 16;
                f16x8 af = load8_f32_f16(Wv + (c0 + n) * 32 + quad * 8);
                f32x4 acc = {0.f, 0.f, 0.f, 0.f};
                acc = __builtin_amdgcn_mfma_f32_16x16x32_f16(af, bfr, acc, 0, 0, 0);
                #pragma unroll
                for (int r = 0; r < 4; ++r) {
                    const int dc = c0 + quad * 4 + r;
                    float v = acc[r] + bv[dc];
                    vtile[(sub * 256 + (dc - cbh)) * 32 + sh + n] = f16bits(v);
                }
            }
            __syncthreads();

            #pragma unroll
            for (int k = 0; k < 8; ++k) {
                const int slot = k * 256 + tid;
                const int li   = slot & 3;
                const int cl   = (slot >> 2) & 255;
                const int sb   = slot >> 10;
                const int c    = cbh + cl;
                const int bh   = b * 8 + (c >> 6);
                const int d    = c & 63;
                const int stile= (s0 >> 5) + sb;
                uint4 vv = *(const uint4*)(vtile + (sb * 256 + cl) * 32 + li * 8);
                *(uint4*)(vws + (((size_t)bh * (S_ / 32) + stile) * 64 + d) * 32 + li * 8) = vv;
            }
            if (half == 0) __syncthreads();  // reuse vtile for second half
        }
        (void)cb;
    }
}

// ---------------------------------------------------------------------------
// Kernel 2: flash attention. R8.
// Round-1 lesson: 8x32-row waves doubled per-work VALU (fragment loads,
// addr calc, AGPR shuffling from the 128-reg cap) -> slower despite 2x
// occupancy. Restore the round-0 4-wave / 64-q-row body (best VALU
// amortization, 88 VGPR + 64 AGPR ~ 152 regs), and instead:
//  - small per-d-tile epilogue transpose (32x36 f32/wave): LDS 54.3->37.9 KB
//    -> reg-bound occupancy 3 blocks/CU = 12 waves/CU (launch_bounds(256,3)).
//  - permlane32_swap packing: 8 swaps replace 16 ds_permute + 32 cndmask
//    per wave-iter.
//  - XCD grid (BH, S/256) retained (FETCH 139->29 MB in round 1).
//  - exp2 softmax (scale*log2e folded into Q projection).
// Staging: 256 thr stage K (4KB) + V (4KB), 16B/thread each, double
// buffered, 2-barrier loop (proven correct, unchanged).
// ---------------------------------------------------------------------------
#define KST 72   // K lds row stride (shorts): 144B, 16B-aligned
#define VST 40   // V lds row stride (shorts): 80B, 16B-aligned
#define OTS 36   // epilogue LDS row stride (f32) for one 32-wide d-tile

__global__ __launch_bounds__(256, 3)
void flash_kernel(const short* __restrict__ qws, const short* __restrict__ kws,
                  const short* __restrict__ vws, float* __restrict__ out)
{
    __shared__ __align__(16) short ldsk[2 * 32 * KST];   //  9216 B
    __shared__ __align__(16) short ldsv[2 * 64 * VST];   // 10240 B
    __shared__ __align__(16) float olds[4 * 32 * OTS];   // 18432 B (tot 37888)

    const int tid  = threadIdx.x;
    const int wave = tid >> 6;
    const int lane = tid & 63;
    const int m32  = lane & 31;
    const int lh   = lane >> 5;          // lane-half
    const int koff = lh * 8;
    const int bh   = blockIdx.x;                     // XCD = bh % 8
    const int q0   = blockIdx.y * 256 + wave * 64;   // 64 q-rows per wave

    const short* qbase = qws + (size_t)bh * S_ * D_;
    const short* kbase = kws + (size_t)bh * S_ * D_;
    const short* vbase = vws + (size_t)bh * (S_ / 32) * 2048;  // blocked tiles

    // staging addresses (per thread, fixed)
    short* kdst0 = ldsk + (tid >> 3) * KST + (tid & 7) * 8;   // K: 8 thr/row of 64
    short* vdst0 = ldsv + (tid >> 2) * VST + (tid & 3) * 8;   // V: 4 thr/row of 32

    // Q^T B-frags (held): qb[qg][h]: B[d=h*16+lh*8+j][q=m32]
    f16x8 qb[2][4];
    #pragma unroll
    for (int qg = 0; qg < 2; ++qg)
        #pragma unroll
        for (int h = 0; h < 4; ++h)
            qb[qg][h] = *(const f16x8*)(qbase + (q0 + qg * 32 + m32) * D_ + h * 16 + koff);

    f32x16 z16;
    #pragma unroll
    for (int r = 0; r < 16; ++r) z16[r] = 0.f;

    f32x16 o[2][2];      // [qg][d-tile] O^T accumulators
    float  pl[2] = {0.f, 0.f};
    #pragma unroll
    for (int qg = 0; qg < 2; ++qg)
        #pragma unroll
        for (int t = 0; t < 2; ++t)
            o[qg][t] = z16;

    // stage tile 0 into buffer 0
    {
        uint4 kr = *(const uint4*)(kbase + (size_t)tid * 8);
        uint4 vr = *(const uint4*)(vbase + (size_t)tid * 8);
        *(uint4*)kdst0 = kr;
        *(uint4*)vdst0 = vr;
    }
    __syncthreads();

    for (int it = 0; it < 64; ++it) {
        const int cur = it & 1, nx = cur ^ 1;

        // issue next-tile global loads early (coalesced 16B/thread, 4KB each)
        uint4 kr, vr;
        if (it < 63) {
            kr = *(const uint4*)(kbase + (size_t)(it + 1) * 2048 + tid * 8);
            vr = *(const uint4*)(vbase + (size_t)(it + 1) * 2048 + tid * 8);
        }

        // ---- compute on buffer cur ----
        const short* kl = ldsk + cur * (32 * KST);
        const short* vl = ldsv + cur * (64 * VST);
        f16x8 kf[4], va[4];
        #pragma unroll
        for (int h = 0; h < 4; ++h)
            kf[h] = *(const f16x8*)(kl + m32 * KST + h * 16 + koff);
        #pragma unroll
        for (int t = 0; t < 2; ++t)
            #pragma unroll
            for (int kh = 0; kh < 2; ++kh)
                va[t * 2 + kh] = *(const f16x8*)(vl + (t * 32 + m32) * VST + kh * 16 + koff);

        #pragma unroll
        for (int qg = 0; qg < 2; ++qg) {
            f32x16 st = __builtin_amdgcn_mfma_f32_32x32x16_f16(kf[0], qb[qg][0], z16, 0, 0, 0);
            #pragma unroll
            for (int h = 1; h < 4; ++h)
                st = __builtin_amdgcn_mfma_f32_32x32x16_f16(kf[h], qb[qg][h], st, 0, 0, 0);

            float p[16];
            #pragma unroll
            for (int r = 0; r < 16; ++r) p[r] = EXP2(st[r]);
            float s01 = (p[0]+p[1]) + (p[2]+p[3]);
            float s23 = (p[4]+p[5]) + (p[6]+p[7]);
            float s45 = (p[8]+p[9]) + (p[10]+p[11]);
            float s67 = (p[12]+p[13]) + (p[14]+p[15]);
            pl[qg] += (s01 + s23) + (s45 + s67);

            unsigned int pk[8];
            #pragma unroll
            for (int i = 0; i < 8; ++i)
                pk[i] = __builtin_bit_cast(unsigned int,
                          __builtin_amdgcn_cvt_pkrtz(p[2 * i], p[2 * i + 1]));
            // pair swaps: after these, bi0 = {pk0,pk1,pk2,pk3}, bi1 = {pk4..pk7}
            pl32swap(pk[0], pk[2]);
            pl32swap(pk[1], pk[3]);
            pl32swap(pk[4], pk[6]);
            pl32swap(pk[5], pk[7]);

            i32x4 bi0, bi1;
            bi0[0] = (int)pk[0]; bi0[1] = (int)pk[1];
            bi0[2] = (int)pk[2]; bi0[3] = (int)pk[3];
            bi1[0] = (int)pk[4]; bi1[1] = (int)pk[5];
            bi1[2] = (int)pk[6]; bi1[3] = (int)pk[7];
            f16x8 bf0 = __builtin_bit_cast(f16x8, bi0);
            f16x8 bf1 = __builtin_bit_cast(f16x8, bi1);

            #pragma unroll
            for (int t = 0; t < 2; ++t) {
                o[qg][t] = __builtin_amdgcn_mfma_f32_32x32x16_f16(va[t * 2 + 0], bf0, o[qg][t], 0, 0, 0);
                o[qg][t] = __builtin_amdgcn_mfma_f32_32x32x16_f16(va[t * 2 + 1], bf1, o[qg][t], 0, 0, 0);
            }
        }

        __syncthreads();   // all waves done reading buffer cur
        if (it < 63) {
            *(uint4*)(kdst0 + nx * (32 * KST)) = kr;
            *(uint4*)(vdst0 + nx * (64 * VST)) = vr;
        }
        __syncthreads();   // staging visible before next iter's reads
    }

    // epilogue: complete row sums across lane-halves, normalize, transpose
    // O^T -> O one 32-wide d-tile at a time through per-wave LDS (32x36 f32),
    // coalesced f32x4 stores (128B per 8 lanes).
    const int b = bh >> 3, h = bh & 7;
    float* ow = olds + wave * (32 * OTS);
    #pragma unroll
    for (int qg = 0; qg < 2; ++qg) {
        float rs = pl[qg] + __shfl_xor(pl[qg], 32);
        float rl = 1.0f / rs;
        #pragma unroll
        for (int t = 0; t < 2; ++t) {
            const f32x16& ot = o[qg][t];
            #pragma unroll
            for (int g = 0; g < 4; ++g) {
                f32x4 w;
                w[0] = ot[g * 4 + 0] * rl;
                w[1] = ot[g * 4 + 1] * rl;
                w[2] = ot[g * 4 + 2] * rl;
                w[3] = ot[g * 4 + 3] * rl;
                // element (q=m32, dcol=r+8g+4lh) of this 32-wide d-tile
                *(f32x4*)(ow + m32 * OTS + 8 * g + 4 * lh) = w;
            }
            #pragma unroll
            for (int c = 0; c < 4; ++c) {
                const int row = (lane >> 3) + 8 * c;       // q-row within 32-row group
                f32x4 v = *(const f32x4*)(ow + row * OTS + (lane & 7) * 4);
                const int sq = q0 + qg * 32 + row;
                *(f32x4*)(out + ((size_t)(b * S_ + sq)) * DPROJ_
                              + h * 64 + t * 32 + (lane & 7) * 4) = v;
            }
        }
    }
}

// ---------------------------------------------------------------------------
extern "C" void kernel_launch(void* const* d_in, const int* in_sizes, int n_in,
                              void* d_out, int out_size, void* d_ws, size_t ws_size,
                              hipStream_t stream)
{
    const float* query = (const float*)d_in[0];
    const float* key   = (const float*)d_in[1];
    const float* value = (const float*)d_in[2];
    // d_in[3] = mask (int32) -- only its shape feeds the reference; unused.
    const float* Wq = (const float*)d_in[4];
    const float* bq = (const float*)d_in[5];
    const float* Wk = (const float*)d_in[6];
    const float* bk = (const float*)d_in[7];
    const float* Wv = (const float*)d_in[8];
    const float* bv = (const float*)d_in[9];

    float* out = (float*)d_out;
    short* ws  = (short*)d_ws;
    const size_t TSZ = (size_t)BH_ * S_ * D_;
    short* qws = ws;
    short* kws = ws + TSZ;
    short* vws = ws + 2 * TSZ;

    proj_kernel<<<dim3((B_ * S_) / 16, 3), 256, 0, stream>>>(
        query, key, value, Wq, bq, Wk, bk, Wv, bv, qws, kws, vws);
    flash_kernel<<<dim3(BH_, S_ / 256), 256, 0, stream>>>(qws, kws, vws, out);
}